// Round 2
// baseline (288.516 us; speedup 1.0000x reference)
//
#include <hip/hip_runtime.h>
#include <math.h>

#define BB 32
#define SS 4096
#define HH 512
#define CHUNKS 32
#define ROWS_PER_BLOCK (SS / CHUNKS)   // 128

// ws layout (float offsets):
//  targets  [2][B][H]          @ 0        (32768)
//  scores   [2][B][S]          @ 32768    (262144)
//  pml      [2][B][CHUNKS][2]  @ 294912   (4096)
//  pacc     [2][B][CHUNKS][H]  @ 299008   (1048576)
#define WS_TARGETS 0
#define WS_SCORES 32768
#define WS_PML 294912
#define WS_PACC 299008

// ---------------------------------------------------------------- K1: targets
__global__ __launch_bounds__(256) void k_target(
    const float* __restrict__ tree_in, const float* __restrict__ text_in,
    const float* __restrict__ W_in, float* __restrict__ ws)
{
    const int b = blockIdx.x;
    const int br = blockIdx.y;
    const float* inp = (br == 0 ? tree_in : text_in) + b * HH;

    __shared__ float sin_[HH];
    for (int i = threadIdx.x; i < HH; i += 256) sin_[i] = inp[i];
    __syncthreads();

    const int h0 = threadIdx.x, h1 = threadIdx.x + 256;
    float acc0 = 0.f, acc1 = 0.f;
    for (int k = 0; k < HH; ++k) {
        const float x = sin_[k];
        acc0 += x * W_in[k * HH + h0];
        acc1 += x * W_in[k * HH + h1];
    }
    float* tgt = ws + WS_TARGETS + (size_t)(br * BB + b) * HH;
    tgt[h0] = acc0;
    tgt[h1] = acc1;
}

// ------------------------------------------------- K2: flash pass over context
// 16-lane groups: 4 rows per wave-iteration; lane (g,q) owns cols q*4 + r*64.
#define LOADROW(BUF, I) do {                                                   \
    const float* _row = ctx + (size_t)(s0 + (I) * 4 + g) * HH + q * 4;         \
    _Pragma("unroll")                                                          \
    for (int r = 0; r < 8; ++r) BUF[r] = *(const float4*)(_row + r * 64);      \
} while (0)

#define COMPUTE(BUF, I) do {                                                   \
    float dr[8];                                                               \
    _Pragma("unroll")                                                          \
    for (int r = 0; r < 8; ++r)                                                \
        dr[r] = BUF[r].x * t[r].x + BUF[r].y * t[r].y +                        \
                BUF[r].z * t[r].z + BUF[r].w * t[r].w;                         \
    float d = ((dr[0] + dr[1]) + (dr[2] + dr[3])) +                            \
              ((dr[4] + dr[5]) + (dr[6] + dr[7]));                             \
    d += __shfl_xor(d, 1); d += __shfl_xor(d, 2);                              \
    d += __shfl_xor(d, 4); d += __shfl_xor(d, 8);                              \
    const int s = s0 + (I) * 4 + g;                                            \
    const float sc = d * mv[I];                                                \
    if (q == 0) scores[s] = sc;                                                \
    if (sc > m + 8.f) {                                                        \
        const float e = __expf(m - sc);                                        \
        l *= e;                                                                \
        _Pragma("unroll")                                                      \
        for (int r = 0; r < 8; ++r) {                                          \
            acc[r].x *= e; acc[r].y *= e; acc[r].z *= e; acc[r].w *= e;        \
        }                                                                      \
        m = sc;                                                                \
    }                                                                          \
    const float p = __expf(sc - m);                                            \
    l += p;                                                                    \
    if (sc > m - 30.f) {                                                       \
        _Pragma("unroll")                                                      \
        for (int r = 0; r < 8; ++r) {                                          \
            acc[r].x += p * BUF[r].x; acc[r].y += p * BUF[r].y;                \
            acc[r].z += p * BUF[r].z; acc[r].w += p * BUF[r].w;                \
        }                                                                      \
    }                                                                          \
} while (0)

__global__ __launch_bounds__(256) void k_flash(
    const float* __restrict__ tree_ctx, const float* __restrict__ text_ctx,
    const float* __restrict__ tree_mask, const float* __restrict__ text_mask,
    float* __restrict__ ws)
{
    const int chunk = blockIdx.x;
    const int b = blockIdx.y;
    const int br = blockIdx.z;

    const float* ctx = (br == 0 ? tree_ctx : text_ctx) + (size_t)b * SS * HH;
    const float* mask = (br == 0 ? tree_mask : text_mask) + (size_t)b * SS;
    const float* tgt = ws + WS_TARGETS + (size_t)(br * BB + b) * HH;
    float* scores = ws + WS_SCORES + (size_t)(br * BB + b) * SS;

    const int wave = threadIdx.x >> 6;
    const int lane = threadIdx.x & 63;
    const int g = lane >> 4;    // group 0..3 (one row each per iteration)
    const int q = lane & 15;    // lane within group

    // target fragment (stays in registers the whole kernel)
    float4 t[8];
    #pragma unroll
    for (int r = 0; r < 8; ++r)
        t[r] = *(const float4*)(tgt + r * 64 + q * 4);

    const int s0 = chunk * ROWS_PER_BLOCK + wave * 32;

    // preload this wave-group's 8 mask values
    float mv[8];
    #pragma unroll
    for (int i = 0; i < 8; ++i) mv[i] = mask[s0 + i * 4 + g];

    float m = -INFINITY, l = 0.f;
    float4 acc[8];
    #pragma unroll
    for (int r = 0; r < 8; ++r) acc[r] = make_float4(0.f, 0.f, 0.f, 0.f);

    float4 cA[8], cB[8];
    LOADROW(cA, 0);
    #pragma unroll
    for (int i = 0; i < 8; i += 2) {
        LOADROW(cB, i + 1);
        COMPUTE(cA, i);
        if (i + 2 < 8) LOADROW(cA, i + 2);
        COMPUTE(cB, i + 1);
    }

    // merge the 4 group-partials within the wave (lanes q,q+16,q+32,q+48 share cols)
    #pragma unroll
    for (int offs = 16; offs <= 32; offs <<= 1) {
        const float mo = __shfl_xor(m, offs);
        const float lo_ = __shfl_xor(l, offs);
        const float M2 = fmaxf(m, mo);
        const float es = __expf(m - M2), eo = __expf(mo - M2);
        l = l * es + lo_ * eo;
        #pragma unroll
        for (int r = 0; r < 8; ++r) {
            float ox = __shfl_xor(acc[r].x, offs);
            float oy = __shfl_xor(acc[r].y, offs);
            float oz = __shfl_xor(acc[r].z, offs);
            float ow = __shfl_xor(acc[r].w, offs);
            acc[r].x = acc[r].x * es + ox * eo;
            acc[r].y = acc[r].y * es + oy * eo;
            acc[r].z = acc[r].z * es + oz * eo;
            acc[r].w = acc[r].w * es + ow * eo;
        }
        m = M2;
    }

    // block combine (4 wave-partials -> 1 block-partial)
    __shared__ float lm[4], ll[4];
    __shared__ float lacc[4][HH];   // 8 KB
    if (lane < 16) {
        if (q == 0) { lm[wave] = m; ll[wave] = l; }
        #pragma unroll
        for (int r = 0; r < 8; ++r)
            *(float4*)&lacc[wave][r * 64 + q * 4] = acc[r];
    }
    __syncthreads();

    const float M = fmaxf(fmaxf(lm[0], lm[1]), fmaxf(lm[2], lm[3]));
    const float e0 = __expf(lm[0] - M);
    const float e1 = __expf(lm[1] - M);
    const float e2 = __expf(lm[2] - M);
    const float e3 = __expf(lm[3] - M);

    float* pml = ws + WS_PML + (size_t)((br * BB + b) * CHUNKS + chunk) * 2;
    float* pacc = ws + WS_PACC + (size_t)((br * BB + b) * CHUNKS + chunk) * HH;
    for (int h = threadIdx.x; h < HH; h += 256)
        pacc[h] = lacc[0][h] * e0 + lacc[1][h] * e1 + lacc[2][h] * e2 + lacc[3][h] * e3;
    if (threadIdx.x == 0) {
        pml[0] = M;
        pml[1] = ll[0] * e0 + ll[1] * e1 + ll[2] * e2 + ll[3] * e3;
    }
}

// ---------------- K3: merge partials -> weighted, att outputs, final GEMV+tanh
__global__ __launch_bounds__(256) void k_tail(
    const float* __restrict__ tree_in, const float* __restrict__ text_in,
    const float* __restrict__ W_out, const float* __restrict__ ws,
    float* __restrict__ out)
{
    const int b = blockIdx.x;

    __shared__ float comb[4 * HH];         // [tree_w, tree_in, text_w, text_in]
    __shared__ float escs[2][CHUNKS];      // exp(m_c - M) * invL
    __shared__ float sM[2], sInvL[2];

    for (int br = 0; br < 2; ++br) {
        const float* pml = ws + WS_PML + (size_t)(br * BB + b) * CHUNKS * 2;
        float M = -INFINITY;
        for (int c = 0; c < CHUNKS; ++c) M = fmaxf(M, pml[2 * c]);
        float L = 0.f;
        for (int c = 0; c < CHUNKS; ++c) L += pml[2 * c + 1] * __expf(pml[2 * c] - M);
        const float invL = 1.f / L;
        if (threadIdx.x < CHUNKS)
            escs[br][threadIdx.x] = __expf(pml[2 * threadIdx.x] - M) * invL;
        if (threadIdx.x == 0) { sM[br] = M; sInvL[br] = invL; }
    }
    __syncthreads();

    // weighted vectors into comb
    for (int br = 0; br < 2; ++br) {
        const float* pacc = ws + WS_PACC + (size_t)(br * BB + b) * CHUNKS * HH;
        for (int h = threadIdx.x; h < HH; h += 256) {
            float a = 0.f;
            for (int c = 0; c < CHUNKS; ++c) a += pacc[(size_t)c * HH + h] * escs[br][c];
            comb[br * 2 * HH + h] = a;
        }
    }
    const float* ti = tree_in + b * HH;
    const float* xi = text_in + b * HH;
    for (int h = threadIdx.x; h < HH; h += 256) {
        comb[HH + h] = ti[h];
        comb[3 * HH + h] = xi[h];
    }

    // attention outputs
    for (int br = 0; br < 2; ++br) {
        const float* scores = ws + WS_SCORES + (size_t)(br * BB + b) * SS;
        float* att = out + BB * HH + (size_t)(br * BB + b) * SS;
        const float M = sM[br], invL = sInvL[br];
        for (int s = threadIdx.x; s < SS; s += 256)
            att[s] = __expf(scores[s] - M) * invL;
    }
    __syncthreads();

    // final GEMV + tanh
    const int h0 = threadIdx.x, h1 = threadIdx.x + 256;
    float a0 = 0.f, a1 = 0.f;
    for (int k = 0; k < 4 * HH; ++k) {
        const float x = comb[k];
        a0 += x * W_out[(size_t)k * HH + h0];
        a1 += x * W_out[(size_t)k * HH + h1];
    }
    out[b * HH + h0] = tanhf(a0);
    out[b * HH + h1] = tanhf(a1);
}

// ---------------------------------------------------------------------- launch
extern "C" void kernel_launch(void* const* d_in, const int* in_sizes, int n_in,
                              void* d_out, int out_size, void* d_ws, size_t ws_size,
                              hipStream_t stream)
{
    const float* tree_inputs  = (const float*)d_in[0];
    const float* tree_context = (const float*)d_in[1];
    const float* text_inputs  = (const float*)d_in[2];
    const float* text_context = (const float*)d_in[3];
    const float* tree_mask    = (const float*)d_in[4];
    const float* text_mask    = (const float*)d_in[5];
    const float* W_in         = (const float*)d_in[6];
    const float* W_out        = (const float*)d_in[7];
    float* out = (float*)d_out;
    float* ws = (float*)d_ws;

    k_target<<<dim3(BB, 2), 256, 0, stream>>>(tree_inputs, text_inputs, W_in, ws);
    k_flash<<<dim3(CHUNKS, BB, 2), 256, 0, stream>>>(tree_context, text_context,
                                                     tree_mask, text_mask, ws);
    k_tail<<<dim3(BB), 256, 0, stream>>>(tree_inputs, text_inputs, W_out, ws, out);
}

// Round 3
// 221.088 us; speedup vs baseline: 1.3050x; 1.3050x over previous
//
#include <hip/hip_runtime.h>
#include <math.h>

#define BB 32
#define SS 4096
#define HH 512
#define CHUNKS 32
#define ROWS_PER_BLOCK 128          // rows per k_flash block
#define ROWS_PER_WAVE 32
#define TROWS 4                     // rows per DMA tile (8 KB)
#define NTILES (ROWS_PER_WAVE / TROWS)   // 8

// ws layout (float offsets):
//  weighted [2][B][H]          @ 0        (32768)   (written by k_tail step2 src: pacc)
//  scores   [2][B][S]          @ 32768    (262144)
//  pml      [2][B][CHUNKS][2]  @ 294912   (4096)
//  pacc     [2][B][CHUNKS][H]  @ 299008   (1048576)
#define WS_TARGETS 0                 // targets live here until k_flash done
#define WS_SCORES 32768
#define WS_PML 294912
#define WS_PACC 299008

__device__ static inline void gload_lds16(const float* g, float* l) {
    __builtin_amdgcn_global_load_lds(
        (const __attribute__((address_space(1))) void*)g,
        (__attribute__((address_space(3))) void*)l,
        16, 0, 0);
}

// ---------------------------------------------------------------- K1: targets
// targets[br][b][:] = inputs[br][b][:] @ W_in ; grid (2 br, BB b, 2 hslice)
__global__ __launch_bounds__(256) void k_target(
    const float* __restrict__ tree_in, const float* __restrict__ text_in,
    const float* __restrict__ W_in, float* __restrict__ ws)
{
    const int br = blockIdx.x;
    const int b = blockIdx.y;
    const int hs = blockIdx.z;
    const float* inp = (br == 0 ? tree_in : text_in) + b * HH;

    __shared__ float sinp[HH];
    __shared__ float lacc[4][256];
    if (threadIdx.x < 128)
        *(float4*)&sinp[threadIdx.x * 4] = *(const float4*)(inp + threadIdx.x * 4);
    __syncthreads();

    const int wave = threadIdx.x >> 6;
    const int lane = threadIdx.x & 63;
    const int hbase = hs * 256 + lane * 4;

    float4 a = make_float4(0.f, 0.f, 0.f, 0.f);
    const float* wrow = W_in + (size_t)(wave * 128) * HH + hbase;
    #pragma unroll 4
    for (int k = 0; k < 128; ++k) {
        const float x = sinp[wave * 128 + k];
        const float4 w = *(const float4*)(wrow + (size_t)k * HH);
        a.x += x * w.x; a.y += x * w.y; a.z += x * w.z; a.w += x * w.w;
    }
    *(float4*)&lacc[wave][lane * 4] = a;
    __syncthreads();

    float v = lacc[0][threadIdx.x] + lacc[1][threadIdx.x]
            + lacc[2][threadIdx.x] + lacc[3][threadIdx.x];
    ws[WS_TARGETS + (size_t)(br * BB + b) * HH + hs * 256 + threadIdx.x] = v;
}

// ------------------------------------------------- K2: flash pass over context
__global__ __launch_bounds__(256) void k_flash(
    const float* __restrict__ tree_ctx, const float* __restrict__ text_ctx,
    const float* __restrict__ tree_mask, const float* __restrict__ text_mask,
    float* __restrict__ ws)
{
    const int chunk = blockIdx.x;
    const int b = blockIdx.y;
    const int br = blockIdx.z;

    const float* ctx = (br == 0 ? tree_ctx : text_ctx) + (size_t)b * SS * HH;
    const float* mask = (br == 0 ? tree_mask : text_mask) + (size_t)b * SS;
    const float* tgt = ws + WS_TARGETS + (size_t)(br * BB + b) * HH;
    float* scores_g = ws + WS_SCORES + (size_t)(br * BB + b) * SS;

    const int wave = threadIdx.x >> 6;
    const int lane = threadIdx.x & 63;
    const int lane4 = lane * 4;

    __shared__ float tiles[4][2][TROWS * HH];   // 64 KB
    __shared__ float smask[ROWS_PER_BLOCK];
    __shared__ float ssc[ROWS_PER_BLOCK];
    __shared__ float lm[4], ll[4];
    __shared__ float lacc[4][HH];               // 8 KB

    if (threadIdx.x < ROWS_PER_BLOCK)
        smask[threadIdx.x] = mask[chunk * ROWS_PER_BLOCK + threadIdx.x];

    // target fragment: lane owns floats [lane*4, +4) and [256+lane*4, +4)
    const float4 t0 = *(const float4*)(tgt + lane4);
    const float4 t1 = *(const float4*)(tgt + 256 + lane4);
    __syncthreads();   // smask ready; drains all vmem (clean vmcnt state)

    float* const buf0 = &tiles[wave][0][0];
    float* const buf1 = &tiles[wave][1][0];
    const int s0 = chunk * ROWS_PER_BLOCK + wave * ROWS_PER_WAVE;
    const int r0 = wave * ROWS_PER_WAVE;

    // issue a 4-row (8 KB) tile: 8 DMA instructions, LDS dst linear
    #define ISSUE_TILE(TT, BP) do {                                          \
        const float* _g = ctx + (size_t)(s0 + (TT) * TROWS) * HH + lane4;    \
        _Pragma("unroll")                                                    \
        for (int j = 0; j < 8; ++j)                                          \
            gload_lds16(_g + j * 256, (BP) + j * 256);                       \
    } while (0)

    float m = -INFINITY, l = 0.f;
    float4 acc_a = make_float4(0.f, 0.f, 0.f, 0.f);
    float4 acc_b = make_float4(0.f, 0.f, 0.f, 0.f);

    ISSUE_TILE(0, buf0);
    for (int tt = 0; tt < NTILES; ++tt) {
        if (tt + 1 < NTILES) {
            float* nb = ((tt + 1) & 1) ? buf1 : buf0;
            ISSUE_TILE(tt + 1, nb);
            asm volatile("s_waitcnt vmcnt(8)" ::: "memory");
        } else {
            asm volatile("s_waitcnt vmcnt(0)" ::: "memory");
        }
        __builtin_amdgcn_sched_barrier(0);

        const float* bp = (tt & 1) ? buf1 : buf0;
        const int rbase = r0 + tt * TROWS;

        // dots (lane partials)
        float d0, d1, d2, d3;
        {
            float4 c0, c1;
            c0 = *(const float4*)(bp + 0 * HH + lane4);
            c1 = *(const float4*)(bp + 0 * HH + 256 + lane4);
            d0 = c0.x*t0.x + c0.y*t0.y + c0.z*t0.z + c0.w*t0.w
               + c1.x*t1.x + c1.y*t1.y + c1.z*t1.z + c1.w*t1.w;
            c0 = *(const float4*)(bp + 1 * HH + lane4);
            c1 = *(const float4*)(bp + 1 * HH + 256 + lane4);
            d1 = c0.x*t0.x + c0.y*t0.y + c0.z*t0.z + c0.w*t0.w
               + c1.x*t1.x + c1.y*t1.y + c1.z*t1.z + c1.w*t1.w;
            c0 = *(const float4*)(bp + 2 * HH + lane4);
            c1 = *(const float4*)(bp + 2 * HH + 256 + lane4);
            d2 = c0.x*t0.x + c0.y*t0.y + c0.z*t0.z + c0.w*t0.w
               + c1.x*t1.x + c1.y*t1.y + c1.z*t1.z + c1.w*t1.w;
            c0 = *(const float4*)(bp + 3 * HH + lane4);
            c1 = *(const float4*)(bp + 3 * HH + 256 + lane4);
            d3 = c0.x*t0.x + c0.y*t0.y + c0.z*t0.z + c0.w*t0.w
               + c1.x*t1.x + c1.y*t1.y + c1.z*t1.z + c1.w*t1.w;
        }
        // 4 interleaved butterfly reduces -> full sum in every lane
        #pragma unroll
        for (int off = 1; off < 64; off <<= 1) {
            d0 += __shfl_xor(d0, off);
            d1 += __shfl_xor(d1, off);
            d2 += __shfl_xor(d2, off);
            d3 += __shfl_xor(d3, off);
        }

        const float sc0 = d0 * smask[rbase + 0];
        const float sc1 = d1 * smask[rbase + 1];
        const float sc2 = d2 * smask[rbase + 2];
        const float sc3 = d3 * smask[rbase + 3];
        if (lane == 0) ssc[rbase + 0] = sc0;
        if (lane == 1) ssc[rbase + 1] = sc1;
        if (lane == 2) ssc[rbase + 2] = sc2;
        if (lane == 3) ssc[rbase + 3] = sc3;

        // deferred-max online softmax (wave-uniform m, l)
        const float mx = fmaxf(fmaxf(sc0, sc1), fmaxf(sc2, sc3));
        if (mx > m + 8.f) {
            const float e = __expf(m - mx);   // m=-inf -> 0
            l *= e;
            acc_a.x *= e; acc_a.y *= e; acc_a.z *= e; acc_a.w *= e;
            acc_b.x *= e; acc_b.y *= e; acc_b.z *= e; acc_b.w *= e;
            m = mx;
        }
        const float p0 = __expf(sc0 - m);
        const float p1 = __expf(sc1 - m);
        const float p2 = __expf(sc2 - m);
        const float p3 = __expf(sc3 - m);
        l += (p0 + p1) + (p2 + p3);

        // weighted accumulate: re-read rows from LDS (cheap)
        {
            float4 c0, c1;
            c0 = *(const float4*)(bp + 0 * HH + lane4);
            c1 = *(const float4*)(bp + 0 * HH + 256 + lane4);
            acc_a.x += p0*c0.x; acc_a.y += p0*c0.y; acc_a.z += p0*c0.z; acc_a.w += p0*c0.w;
            acc_b.x += p0*c1.x; acc_b.y += p0*c1.y; acc_b.z += p0*c1.z; acc_b.w += p0*c1.w;
            c0 = *(const float4*)(bp + 1 * HH + lane4);
            c1 = *(const float4*)(bp + 1 * HH + 256 + lane4);
            acc_a.x += p1*c0.x; acc_a.y += p1*c0.y; acc_a.z += p1*c0.z; acc_a.w += p1*c0.w;
            acc_b.x += p1*c1.x; acc_b.y += p1*c1.y; acc_b.z += p1*c1.z; acc_b.w += p1*c1.w;
            c0 = *(const float4*)(bp + 2 * HH + lane4);
            c1 = *(const float4*)(bp + 2 * HH + 256 + lane4);
            acc_a.x += p2*c0.x; acc_a.y += p2*c0.y; acc_a.z += p2*c0.z; acc_a.w += p2*c0.w;
            acc_b.x += p2*c1.x; acc_b.y += p2*c1.y; acc_b.z += p2*c1.z; acc_b.w += p2*c1.w;
            c0 = *(const float4*)(bp + 3 * HH + lane4);
            c1 = *(const float4*)(bp + 3 * HH + 256 + lane4);
            acc_a.x += p3*c0.x; acc_a.y += p3*c0.y; acc_a.z += p3*c0.z; acc_a.w += p3*c0.w;
            acc_b.x += p3*c1.x; acc_b.y += p3*c1.y; acc_b.z += p3*c1.z; acc_b.w += p3*c1.w;
        }
    }
    #undef ISSUE_TILE

    // block combine (4 wave-partials -> 1 block-partial)
    if (lane == 0) { lm[wave] = m; ll[wave] = l; }
    *(float4*)&lacc[wave][lane4] = acc_a;
    *(float4*)&lacc[wave][256 + lane4] = acc_b;
    __syncthreads();

    const float M = fmaxf(fmaxf(lm[0], lm[1]), fmaxf(lm[2], lm[3]));
    const float e0 = __expf(lm[0] - M);
    const float e1 = __expf(lm[1] - M);
    const float e2 = __expf(lm[2] - M);
    const float e3 = __expf(lm[3] - M);

    float* pml = ws + WS_PML + (size_t)((br * BB + b) * CHUNKS + chunk) * 2;
    float* pacc = ws + WS_PACC + (size_t)((br * BB + b) * CHUNKS + chunk) * HH;
    for (int h = threadIdx.x; h < HH; h += 256)
        pacc[h] = lacc[0][h] * e0 + lacc[1][h] * e1 + lacc[2][h] * e2 + lacc[3][h] * e3;
    if (threadIdx.x == 0) {
        pml[0] = M;
        pml[1] = ll[0] * e0 + ll[1] * e1 + ll[2] * e2 + ll[3] * e3;
    }
    if (threadIdx.x < ROWS_PER_BLOCK)
        scores_g[chunk * ROWS_PER_BLOCK + threadIdx.x] = ssc[threadIdx.x];
}

// ------------- K3: merge partials, att outputs, combined = tanh(concat@W_out)
// grid (2 half, BB b): block computes out[b][half*256 .. +256) and att[half]
__global__ __launch_bounds__(256) void k_tail(
    const float* __restrict__ tree_in, const float* __restrict__ text_in,
    const float* __restrict__ W_out, const float* __restrict__ ws,
    float* __restrict__ out)
{
    const int half = blockIdx.x;
    const int b = blockIdx.y;
    const int tid = threadIdx.x;

    __shared__ float comb[4 * HH];      // 8 KB
    __shared__ float esc[2][CHUNKS];
    __shared__ float lacc[4][256];      // 4 KB
    __shared__ float sM[2], sL[2];

    for (int br = 0; br < 2; ++br) {
        const float* pml = ws + WS_PML + (size_t)(br * BB + b) * CHUNKS * 2;
        float M = -INFINITY;
        for (int c = 0; c < CHUNKS; ++c) M = fmaxf(M, pml[2 * c]);
        float L = 0.f;
        for (int c = 0; c < CHUNKS; ++c) L += pml[2 * c + 1] * __expf(pml[2 * c] - M);
        const float invL = 1.f / L;
        if (tid < CHUNKS) esc[br][tid] = __expf(pml[2 * tid] - M) * invL;
        if (tid == 0) { sM[br] = M; sL[br] = invL; }
    }
    __syncthreads();

    // comb = [tree_w | tree_in | text_w | text_in]
    {
        const float* pacc0 = ws + WS_PACC + (size_t)(0 * BB + b) * CHUNKS * HH;
        const float* pacc1 = ws + WS_PACC + (size_t)(1 * BB + b) * CHUNKS * HH;
        for (int h = tid; h < HH; h += 256) {
            float a0 = 0.f, a1 = 0.f;
            for (int c = 0; c < CHUNKS; ++c) {
                a0 += pacc0[(size_t)c * HH + h] * esc[0][c];
                a1 += pacc1[(size_t)c * HH + h] * esc[1][c];
            }
            comb[h] = a0;
            comb[2 * HH + h] = a1;
            comb[HH + h] = tree_in[b * HH + h];
            comb[3 * HH + h] = text_in[b * HH + h];
        }
    }
    // att output for branch == half
    {
        const float* sc_g = ws + WS_SCORES + (size_t)(half * BB + b) * SS;
        float* att = out + BB * HH + (size_t)(half * BB + b) * SS;
        const float M = sM[half], invL = sL[half];
        for (int s = tid; s < SS; s += 256)
            att[s] = __expf(sc_g[s] - M) * invL;
    }
    __syncthreads();

    // GEMV: out[b][half*256+j] = tanh(sum_k comb[k] * W_out[k][half*256+j])
    const int wave = tid >> 6;
    const int lane = tid & 63;
    const int hbase = half * 256 + lane * 4;
    float4 a = make_float4(0.f, 0.f, 0.f, 0.f);
    const float* wrow = W_out + (size_t)(wave * 512) * HH + hbase;
    #pragma unroll 4
    for (int k = 0; k < 512; ++k) {
        const float x = comb[wave * 512 + k];
        const float4 w = *(const float4*)(wrow + (size_t)k * HH);
        a.x += x * w.x; a.y += x * w.y; a.z += x * w.z; a.w += x * w.w;
    }
    *(float4*)&lacc[wave][lane * 4] = a;
    __syncthreads();

    const float v = lacc[0][tid] + lacc[1][tid] + lacc[2][tid] + lacc[3][tid];
    out[b * HH + half * 256 + tid] = tanhf(v);
}

// ---------------------------------------------------------------------- launch
extern "C" void kernel_launch(void* const* d_in, const int* in_sizes, int n_in,
                              void* d_out, int out_size, void* d_ws, size_t ws_size,
                              hipStream_t stream)
{
    const float* tree_inputs  = (const float*)d_in[0];
    const float* tree_context = (const float*)d_in[1];
    const float* text_inputs  = (const float*)d_in[2];
    const float* text_context = (const float*)d_in[3];
    const float* tree_mask    = (const float*)d_in[4];
    const float* text_mask    = (const float*)d_in[5];
    const float* W_in         = (const float*)d_in[6];
    const float* W_out        = (const float*)d_in[7];
    float* out = (float*)d_out;
    float* ws = (float*)d_ws;

    k_target<<<dim3(2, BB, 2), 256, 0, stream>>>(tree_inputs, text_inputs, W_in, ws);
    k_flash<<<dim3(CHUNKS, BB, 2), 256, 0, stream>>>(tree_context, text_context,
                                                     tree_mask, text_mask, ws);
    k_tail<<<dim3(2, BB), 256, 0, stream>>>(tree_inputs, text_inputs, W_out, ws, out);
}

// Round 4
// 126.015 us; speedup vs baseline: 2.2895x; 1.7545x over previous
//
#include <hip/hip_runtime.h>
#include <math.h>

#define BB 32
#define SS 4096
#define HH 512
#define CHUNKS 32
#define ROWS_PER_BLOCK 128          // rows per k_flash block
#define ROWS_PER_WAVE 32
#define TROWS 4                     // rows per DMA tile (8 KB)
#define NTILES (ROWS_PER_WAVE / TROWS)   // 8

// ws layout (float offsets):
#define WS_TPART    0               // [8][64][512]  target partials   (262144)
#define WS_SCORES   262144          // [2][B][S]                        (262144)
#define WS_PML      524288          // [2][B][CHUNKS][2]                (4096)
#define WS_PACC     528384          // [2][B][CHUNKS][H]                (1048576)
#define WS_WEIGHTED 1576960         // [2][B][H]                        (32768)
#define WS_GPART    1609728         // [8][2][32][256]                  (131072)

__device__ static inline void gload_lds16(const float* g, float* l) {
    __builtin_amdgcn_global_load_lds(
        (const __attribute__((address_space(1))) void*)g,
        (__attribute__((address_space(3))) void*)l, 16, 0, 0);
}
__device__ static inline void gload_lds16_nt(const float* g, float* l) {
    __builtin_amdgcn_global_load_lds(
        (const __attribute__((address_space(1))) void*)g,
        (__attribute__((address_space(3))) void*)l, 16, 0, 2 /* NT */);
}

// --------------------------------------------- K1: target partial GEMV
// grid (8 rc, 64 bb); tpart[rc][bb][c] = sum_{j in rc-slice} inp[j]*W_in[j][c]
__global__ __launch_bounds__(256) void k_target(
    const float* __restrict__ tree_in, const float* __restrict__ text_in,
    const float* __restrict__ W_in, float* __restrict__ ws)
{
    const int rc = blockIdx.x;
    const int bb = blockIdx.y;          // br*32 + b
    const int br = bb >> 5, b = bb & 31;
    const float* inp = (br == 0 ? tree_in : text_in) + b * HH;

    __shared__ float sx[64];
    if (threadIdx.x < 64) sx[threadIdx.x] = inp[rc * 64 + threadIdx.x];
    __syncthreads();

    const int c = threadIdx.x;
    const float* wp = W_in + (size_t)(rc * 64) * HH + c;
    float a0 = 0.f, a1 = 0.f;
    #pragma unroll 8
    for (int j = 0; j < 64; ++j) {
        const float x = sx[j];
        a0 += x * wp[(size_t)j * HH];
        a1 += x * wp[(size_t)j * HH + 256];
    }
    float* tp = ws + WS_TPART + (size_t)(rc * 64 + bb) * HH;
    tp[c] = a0;
    tp[c + 256] = a1;
}

// ------------------------------------------------- K2: flash pass over context
__global__ __launch_bounds__(256) void k_flash(
    const float* __restrict__ tree_ctx, const float* __restrict__ text_ctx,
    const float* __restrict__ tree_mask, const float* __restrict__ text_mask,
    float* __restrict__ ws)
{
    const int chunk = blockIdx.x;
    const int b = blockIdx.y;
    const int br = blockIdx.z;
    const int bi = br * BB + b;

    const float* ctx = (br == 0 ? tree_ctx : text_ctx) + (size_t)b * SS * HH;
    const float* mask = (br == 0 ? tree_mask : text_mask) + (size_t)b * SS;
    float* scores_g = ws + WS_SCORES + (size_t)bi * SS;

    const int wave = threadIdx.x >> 6;
    const int lane = threadIdx.x & 63;
    const int lane4 = lane * 4;

    __shared__ float tiles[4][2][TROWS * HH];   // 64 KB
    __shared__ float smask[ROWS_PER_BLOCK];
    __shared__ float ssc[ROWS_PER_BLOCK];
    __shared__ float lm[4], ll[4];
    __shared__ float lacc[4][HH];               // 8 KB

    if (threadIdx.x < ROWS_PER_BLOCK)
        smask[threadIdx.x] = mask[chunk * ROWS_PER_BLOCK + threadIdx.x];

    // target fragment = sum of 8 partials; lane owns [lane*4,+4) and [256+lane*4,+4)
    float4 t0 = make_float4(0.f, 0.f, 0.f, 0.f);
    float4 t1 = make_float4(0.f, 0.f, 0.f, 0.f);
    #pragma unroll
    for (int rc = 0; rc < 8; ++rc) {
        const float* tp = ws + WS_TPART + (size_t)(rc * 64 + bi) * HH;
        const float4 u = *(const float4*)(tp + lane4);
        const float4 v = *(const float4*)(tp + 256 + lane4);
        t0.x += u.x; t0.y += u.y; t0.z += u.z; t0.w += u.w;
        t1.x += v.x; t1.y += v.y; t1.z += v.z; t1.w += v.w;
    }
    __syncthreads();   // smask ready; vmem quiesced before DMA pipeline

    float* const buf0 = &tiles[wave][0][0];
    float* const buf1 = &tiles[wave][1][0];
    const int s0 = chunk * ROWS_PER_BLOCK + wave * ROWS_PER_WAVE;
    const int r0 = wave * ROWS_PER_WAVE;

    // issue a 4-row (8 KB) tile: 8 DMA instrs; text branch = non-temporal
    #define ISSUE_TILE(TT, BP) do {                                          \
        const float* _g = ctx + (size_t)(s0 + (TT) * TROWS) * HH + lane4;    \
        if (br == 0) {                                                       \
            _Pragma("unroll")                                                \
            for (int j = 0; j < 8; ++j)                                      \
                gload_lds16(_g + j * 256, (BP) + j * 256);                   \
        } else {                                                             \
            _Pragma("unroll")                                                \
            for (int j = 0; j < 8; ++j)                                      \
                gload_lds16_nt(_g + j * 256, (BP) + j * 256);                \
        }                                                                    \
    } while (0)

    float m = -INFINITY, l = 0.f;
    float4 acc_a = make_float4(0.f, 0.f, 0.f, 0.f);
    float4 acc_b = make_float4(0.f, 0.f, 0.f, 0.f);

    ISSUE_TILE(0, buf0);
    for (int tt = 0; tt < NTILES; ++tt) {
        if (tt + 1 < NTILES) {
            float* nb = ((tt + 1) & 1) ? buf1 : buf0;
            ISSUE_TILE(tt + 1, nb);
            asm volatile("s_waitcnt vmcnt(8)" ::: "memory");
        } else {
            asm volatile("s_waitcnt vmcnt(0)" ::: "memory");
        }
        __builtin_amdgcn_sched_barrier(0);

        const float* bp = (tt & 1) ? buf1 : buf0;
        const int rbase = r0 + tt * TROWS;

        float d0, d1, d2, d3;
        {
            float4 c0, c1;
            c0 = *(const float4*)(bp + 0 * HH + lane4);
            c1 = *(const float4*)(bp + 0 * HH + 256 + lane4);
            d0 = c0.x*t0.x + c0.y*t0.y + c0.z*t0.z + c0.w*t0.w
               + c1.x*t1.x + c1.y*t1.y + c1.z*t1.z + c1.w*t1.w;
            c0 = *(const float4*)(bp + 1 * HH + lane4);
            c1 = *(const float4*)(bp + 1 * HH + 256 + lane4);
            d1 = c0.x*t0.x + c0.y*t0.y + c0.z*t0.z + c0.w*t0.w
               + c1.x*t1.x + c1.y*t1.y + c1.z*t1.z + c1.w*t1.w;
            c0 = *(const float4*)(bp + 2 * HH + lane4);
            c1 = *(const float4*)(bp + 2 * HH + 256 + lane4);
            d2 = c0.x*t0.x + c0.y*t0.y + c0.z*t0.z + c0.w*t0.w
               + c1.x*t1.x + c1.y*t1.y + c1.z*t1.z + c1.w*t1.w;
            c0 = *(const float4*)(bp + 3 * HH + lane4);
            c1 = *(const float4*)(bp + 3 * HH + 256 + lane4);
            d3 = c0.x*t0.x + c0.y*t0.y + c0.z*t0.z + c0.w*t0.w
               + c1.x*t1.x + c1.y*t1.y + c1.z*t1.z + c1.w*t1.w;
        }
        #pragma unroll
        for (int off = 1; off < 64; off <<= 1) {
            d0 += __shfl_xor(d0, off);
            d1 += __shfl_xor(d1, off);
            d2 += __shfl_xor(d2, off);
            d3 += __shfl_xor(d3, off);
        }

        const float sc0 = d0 * smask[rbase + 0];
        const float sc1 = d1 * smask[rbase + 1];
        const float sc2 = d2 * smask[rbase + 2];
        const float sc3 = d3 * smask[rbase + 3];
        if (lane == 0) ssc[rbase + 0] = sc0;
        if (lane == 1) ssc[rbase + 1] = sc1;
        if (lane == 2) ssc[rbase + 2] = sc2;
        if (lane == 3) ssc[rbase + 3] = sc3;

        const float mx = fmaxf(fmaxf(sc0, sc1), fmaxf(sc2, sc3));
        if (mx > m + 8.f) {
            const float e = __expf(m - mx);   // m=-inf -> 0
            l *= e;
            acc_a.x *= e; acc_a.y *= e; acc_a.z *= e; acc_a.w *= e;
            acc_b.x *= e; acc_b.y *= e; acc_b.z *= e; acc_b.w *= e;
            m = mx;
        }
        const float p0 = __expf(sc0 - m);
        const float p1 = __expf(sc1 - m);
        const float p2 = __expf(sc2 - m);
        const float p3 = __expf(sc3 - m);
        l += (p0 + p1) + (p2 + p3);

        {
            float4 c0, c1;
            c0 = *(const float4*)(bp + 0 * HH + lane4);
            c1 = *(const float4*)(bp + 0 * HH + 256 + lane4);
            acc_a.x += p0*c0.x; acc_a.y += p0*c0.y; acc_a.z += p0*c0.z; acc_a.w += p0*c0.w;
            acc_b.x += p0*c1.x; acc_b.y += p0*c1.y; acc_b.z += p0*c1.z; acc_b.w += p0*c1.w;
            c0 = *(const float4*)(bp + 1 * HH + lane4);
            c1 = *(const float4*)(bp + 1 * HH + 256 + lane4);
            acc_a.x += p1*c0.x; acc_a.y += p1*c0.y; acc_a.z += p1*c0.z; acc_a.w += p1*c0.w;
            acc_b.x += p1*c1.x; acc_b.y += p1*c1.y; acc_b.z += p1*c1.z; acc_b.w += p1*c1.w;
            c0 = *(const float4*)(bp + 2 * HH + lane4);
            c1 = *(const float4*)(bp + 2 * HH + 256 + lane4);
            acc_a.x += p2*c0.x; acc_a.y += p2*c0.y; acc_a.z += p2*c0.z; acc_a.w += p2*c0.w;
            acc_b.x += p2*c1.x; acc_b.y += p2*c1.y; acc_b.z += p2*c1.z; acc_b.w += p2*c1.w;
            c0 = *(const float4*)(bp + 3 * HH + lane4);
            c1 = *(const float4*)(bp + 3 * HH + 256 + lane4);
            acc_a.x += p3*c0.x; acc_a.y += p3*c0.y; acc_a.z += p3*c0.z; acc_a.w += p3*c0.w;
            acc_b.x += p3*c1.x; acc_b.y += p3*c1.y; acc_b.z += p3*c1.z; acc_b.w += p3*c1.w;
        }
    }
    #undef ISSUE_TILE

    if (lane == 0) { lm[wave] = m; ll[wave] = l; }
    *(float4*)&lacc[wave][lane4] = acc_a;
    *(float4*)&lacc[wave][256 + lane4] = acc_b;
    __syncthreads();

    const float M = fmaxf(fmaxf(lm[0], lm[1]), fmaxf(lm[2], lm[3]));
    const float e0 = __expf(lm[0] - M);
    const float e1 = __expf(lm[1] - M);
    const float e2 = __expf(lm[2] - M);
    const float e3 = __expf(lm[3] - M);

    float* pml = ws + WS_PML + (size_t)(bi * CHUNKS + chunk) * 2;
    float* pacc = ws + WS_PACC + (size_t)(bi * CHUNKS + chunk) * HH;
    for (int h = threadIdx.x; h < HH; h += 256)
        pacc[h] = lacc[0][h] * e0 + lacc[1][h] * e1 + lacc[2][h] * e2 + lacc[3][h] * e3;
    if (threadIdx.x == 0) {
        pml[0] = M;
        pml[1] = ll[0] * e0 + ll[1] * e1 + ll[2] * e2 + ll[3] * e3;
    }
    if (threadIdx.x < ROWS_PER_BLOCK)
        scores_g[chunk * ROWS_PER_BLOCK + threadIdx.x] = ssc[threadIdx.x];
}

// -------------------- K3: merge partials -> weighted + att ; grid (2,32,4)
__global__ __launch_bounds__(256) void k_merge(
    const float* __restrict__ ws_ro, float* __restrict__ ws, float* __restrict__ out)
{
    const int br = blockIdx.x;
    const int b = blockIdx.y;
    const int hs = blockIdx.z;
    const int bi = br * BB + b;
    const int tid = threadIdx.x;

    const float* pml = ws_ro + WS_PML + (size_t)bi * CHUNKS * 2;
    __shared__ float esc[CHUNKS];
    float M = -INFINITY;
    for (int c = 0; c < CHUNKS; ++c) M = fmaxf(M, pml[2 * c]);
    float L = 0.f;
    for (int c = 0; c < CHUNKS; ++c) L += pml[2 * c + 1] * __expf(pml[2 * c] - M);
    const float invL = 1.f / L;
    if (tid < CHUNKS) esc[tid] = __expf(pml[2 * tid] - M) * invL;
    __syncthreads();

    // weighted slice (128 h per block)
    const float* pacc = ws_ro + WS_PACC + (size_t)bi * CHUNKS * HH;
    float* wt = ws + WS_WEIGHTED + (size_t)bi * HH;
    if (tid < 128) {
        const int h = hs * 128 + tid;
        float a = 0.f;
        for (int c = 0; c < CHUNKS; ++c) a += pacc[(size_t)c * HH + h] * esc[c];
        wt[h] = a;
    }

    // att slice (1024 s per block)
    const float* sc_g = ws_ro + WS_SCORES + (size_t)bi * SS;
    float* att = out + BB * HH + (size_t)bi * SS;
    for (int s = hs * 1024 + tid; s < hs * 1024 + 1024; s += 256)
        att[s] = __expf(sc_g[s] - M) * invL;
}

// -------------------- K4: partial GEMV of combined @ W_out ; grid (8,2,32)
__global__ __launch_bounds__(256) void k_gemv(
    const float* __restrict__ tree_in, const float* __restrict__ text_in,
    const float* __restrict__ W_out, const float* __restrict__ ws_ro,
    float* __restrict__ ws)
{
    const int rc = blockIdx.x;      // 256-row slice of the 2048 rows
    const int half = blockIdx.y;    // 256-col half
    const int b = blockIdx.z;
    const int tid = threadIdx.x;

    // comb = [tree_w | tree_in | text_w | text_in]
    const int seg = rc >> 1;
    const float* src;
    if (seg == 0)      src = ws_ro + WS_WEIGHTED + (size_t)(0 * BB + b) * HH;
    else if (seg == 1) src = tree_in + (size_t)b * HH;
    else if (seg == 2) src = ws_ro + WS_WEIGHTED + (size_t)(1 * BB + b) * HH;
    else               src = text_in + (size_t)b * HH;

    __shared__ float sx[256];
    sx[tid] = src[(rc & 1) * 256 + tid];
    __syncthreads();

    const float* wp = W_out + (size_t)(rc * 256) * HH + half * 256 + tid;
    float a = 0.f;
    #pragma unroll 8
    for (int j = 0; j < 256; ++j)
        a += sx[j] * wp[(size_t)j * HH];

    ws[WS_GPART + (size_t)((rc * 2 + half) * BB + b) * 256 + tid] = a;
}

// -------------------- K5: reduce partials + tanh ; grid (2,32)
__global__ __launch_bounds__(256) void k_fin(
    const float* __restrict__ ws, float* __restrict__ out)
{
    const int half = blockIdx.x;
    const int b = blockIdx.y;
    const int tid = threadIdx.x;
    float v = 0.f;
    #pragma unroll
    for (int rc = 0; rc < 8; ++rc)
        v += ws[WS_GPART + (size_t)((rc * 2 + half) * BB + b) * 256 + tid];
    out[(size_t)b * HH + half * 256 + tid] = tanhf(v);
}

// ---------------------------------------------------------------------- launch
extern "C" void kernel_launch(void* const* d_in, const int* in_sizes, int n_in,
                              void* d_out, int out_size, void* d_ws, size_t ws_size,
                              hipStream_t stream)
{
    const float* tree_inputs  = (const float*)d_in[0];
    const float* tree_context = (const float*)d_in[1];
    const float* text_inputs  = (const float*)d_in[2];
    const float* text_context = (const float*)d_in[3];
    const float* tree_mask    = (const float*)d_in[4];
    const float* text_mask    = (const float*)d_in[5];
    const float* W_in         = (const float*)d_in[6];
    const float* W_out        = (const float*)d_in[7];
    float* out = (float*)d_out;
    float* ws = (float*)d_ws;

    k_target<<<dim3(8, 64), 256, 0, stream>>>(tree_inputs, text_inputs, W_in, ws);
    k_flash<<<dim3(CHUNKS, BB, 2), 256, 0, stream>>>(tree_context, text_context,
                                                     tree_mask, text_mask, ws);
    k_merge<<<dim3(2, BB, 4), 256, 0, stream>>>(ws, ws, out);
    k_gemv<<<dim3(8, 2, BB), 256, 0, stream>>>(tree_inputs, text_inputs, W_out, ws, ws);
    k_fin<<<dim3(2, BB), 256, 0, stream>>>(ws, out);
}

// Round 5
// 120.741 us; speedup vs baseline: 2.3895x; 1.0437x over previous
//
#include <hip/hip_runtime.h>
#include <math.h>

#define BB 32
#define SS 4096
#define HH 512
#define CHUNKS 32
#define ROWS_PER_BLOCK 128          // rows per k_flash block
#define ROWS_PER_WAVE 32
#define TROWS 4                     // rows per DMA tile (8 KB)
#define NTILES (ROWS_PER_WAVE / TROWS)   // 8

// ws layout (float offsets):
#define WS_TPART    0               // [8][64][512]  target partials   (262144)
#define WS_SCORES   262144          // [2][B][S]                        (262144)
#define WS_PML      524288          // [2][B][CHUNKS][2]                (4096)
#define WS_PACC     528384          // [2][B][CHUNKS][H]                (1048576)
#define WS_WEIGHTED 1576960         // [2][B][H]                        (32768)
#define WS_GPART    1609728         // [8][2][32][256]                  (131072)

__device__ static inline void gload_lds16(const float* g, float* l) {
    __builtin_amdgcn_global_load_lds(
        (const __attribute__((address_space(1))) void*)g,
        (__attribute__((address_space(3))) void*)l, 16, 0, 0);
}
__device__ static inline void gload_lds16_nt(const float* g, float* l) {
    __builtin_amdgcn_global_load_lds(
        (const __attribute__((address_space(1))) void*)g,
        (__attribute__((address_space(3))) void*)l, 16, 0, 2 /* NT */);
}

// --------------------------------------------- K1: target partial GEMV
// grid (8 rc, 64 bb); tpart[rc][bb][c] = sum_{j in rc-slice} inp[j]*W_in[j][c]
__global__ __launch_bounds__(256) void k_target(
    const float* __restrict__ tree_in, const float* __restrict__ text_in,
    const float* __restrict__ W_in, float* __restrict__ ws)
{
    const int rc = blockIdx.x;
    const int bb = blockIdx.y;          // br*32 + b
    const int br = bb >> 5, b = bb & 31;
    const float* inp = (br == 0 ? tree_in : text_in) + b * HH;

    __shared__ float sx[64];
    if (threadIdx.x < 64) sx[threadIdx.x] = inp[rc * 64 + threadIdx.x];
    __syncthreads();

    const int c = threadIdx.x;
    const float* wp = W_in + (size_t)(rc * 64) * HH + c;
    float a0 = 0.f, a1 = 0.f;
    #pragma unroll 8
    for (int j = 0; j < 64; ++j) {
        const float x = sx[j];
        a0 += x * wp[(size_t)j * HH];
        a1 += x * wp[(size_t)j * HH + 256];
    }
    float* tp = ws + WS_TPART + (size_t)(rc * 64 + bb) * HH;
    tp[c] = a0;
    tp[c + 256] = a1;
}

// ------------------------------------------------- K2: flash pass over context
// grid (2 br FASTEST, CHUNKS, BB): interleaves L3-resident tree blocks with
// HBM-NT text blocks in every residency wave -> both read paths run in parallel.
__global__ __launch_bounds__(256) void k_flash(
    const float* __restrict__ tree_ctx, const float* __restrict__ text_ctx,
    const float* __restrict__ tree_mask, const float* __restrict__ text_mask,
    float* __restrict__ ws)
{
    const int br = blockIdx.x;
    const int chunk = blockIdx.y;
    const int b = blockIdx.z;
    const int bi = br * BB + b;

    const float* ctx = (br == 0 ? tree_ctx : text_ctx) + (size_t)b * SS * HH;
    const float* mask = (br == 0 ? tree_mask : text_mask) + (size_t)b * SS;
    float* scores_g = ws + WS_SCORES + (size_t)bi * SS;

    const int wave = threadIdx.x >> 6;
    const int lane = threadIdx.x & 63;
    const int lane4 = lane * 4;

    __shared__ float tiles[4][2][TROWS * HH];   // 64 KB
    __shared__ float smask[ROWS_PER_BLOCK];
    __shared__ float ssc[ROWS_PER_BLOCK];
    __shared__ float lm[4], ll[4];
    __shared__ float lacc[4][HH];               // 8 KB

    float* const buf0 = &tiles[wave][0][0];
    float* const buf1 = &tiles[wave][1][0];
    const int s0 = chunk * ROWS_PER_BLOCK + wave * ROWS_PER_WAVE;
    const int r0 = wave * ROWS_PER_WAVE;

    // issue a 4-row (8 KB) tile: 8 DMA instrs; text branch = non-temporal
    #define ISSUE_TILE(TT, BP) do {                                          \
        const float* _g = ctx + (size_t)(s0 + (TT) * TROWS) * HH + lane4;    \
        if (br == 0) {                                                       \
            _Pragma("unroll")                                                \
            for (int j = 0; j < 8; ++j)                                      \
                gload_lds16(_g + j * 256, (BP) + j * 256);                   \
        } else {                                                             \
            _Pragma("unroll")                                                \
            for (int j = 0; j < 8; ++j)                                      \
                gload_lds16_nt(_g + j * 256, (BP) + j * 256);                \
        }                                                                    \
    } while (0)

    // start the DMA pipeline FIRST, so tile0 streams while we fetch targets
    ISSUE_TILE(0, buf0);
    __builtin_amdgcn_sched_barrier(0);

    if (threadIdx.x < ROWS_PER_BLOCK)
        smask[threadIdx.x] = mask[chunk * ROWS_PER_BLOCK + threadIdx.x];

    // target fragment = sum of 8 partials; lane owns [lane*4,+4) and [256+lane*4,+4)
    float4 t0 = make_float4(0.f, 0.f, 0.f, 0.f);
    float4 t1 = make_float4(0.f, 0.f, 0.f, 0.f);
    #pragma unroll
    for (int rc = 0; rc < 8; ++rc) {
        const float* tp = ws + WS_TPART + (size_t)(rc * 64 + bi) * HH;
        const float4 u = *(const float4*)(tp + lane4);
        const float4 v = *(const float4*)(tp + 256 + lane4);
        t0.x += u.x; t0.y += u.y; t0.z += u.z; t0.w += u.w;
        t1.x += v.x; t1.y += v.y; t1.z += v.z; t1.w += v.w;
    }
    __syncthreads();   // smask ready; drains vmem -> clean vmcnt state (tile0 done)

    float m = -INFINITY, l = 0.f;
    float4 acc_a = make_float4(0.f, 0.f, 0.f, 0.f);
    float4 acc_b = make_float4(0.f, 0.f, 0.f, 0.f);

    for (int tt = 0; tt < NTILES; ++tt) {
        if (tt + 1 < NTILES) {
            float* nb = ((tt + 1) & 1) ? buf1 : buf0;
            ISSUE_TILE(tt + 1, nb);
            asm volatile("s_waitcnt vmcnt(8)" ::: "memory");
        } else {
            asm volatile("s_waitcnt vmcnt(0)" ::: "memory");
        }
        __builtin_amdgcn_sched_barrier(0);

        const float* bp = (tt & 1) ? buf1 : buf0;
        const int rbase = r0 + tt * TROWS;

        float d0, d1, d2, d3;
        {
            float4 c0, c1;
            c0 = *(const float4*)(bp + 0 * HH + lane4);
            c1 = *(const float4*)(bp + 0 * HH + 256 + lane4);
            d0 = c0.x*t0.x + c0.y*t0.y + c0.z*t0.z + c0.w*t0.w
               + c1.x*t1.x + c1.y*t1.y + c1.z*t1.z + c1.w*t1.w;
            c0 = *(const float4*)(bp + 1 * HH + lane4);
            c1 = *(const float4*)(bp + 1 * HH + 256 + lane4);
            d1 = c0.x*t0.x + c0.y*t0.y + c0.z*t0.z + c0.w*t0.w
               + c1.x*t1.x + c1.y*t1.y + c1.z*t1.z + c1.w*t1.w;
            c0 = *(const float4*)(bp + 2 * HH + lane4);
            c1 = *(const float4*)(bp + 2 * HH + 256 + lane4);
            d2 = c0.x*t0.x + c0.y*t0.y + c0.z*t0.z + c0.w*t0.w
               + c1.x*t1.x + c1.y*t1.y + c1.z*t1.z + c1.w*t1.w;
            c0 = *(const float4*)(bp + 3 * HH + lane4);
            c1 = *(const float4*)(bp + 3 * HH + 256 + lane4);
            d3 = c0.x*t0.x + c0.y*t0.y + c0.z*t0.z + c0.w*t0.w
               + c1.x*t1.x + c1.y*t1.y + c1.z*t1.z + c1.w*t1.w;
        }
        #pragma unroll
        for (int off = 1; off < 64; off <<= 1) {
            d0 += __shfl_xor(d0, off);
            d1 += __shfl_xor(d1, off);
            d2 += __shfl_xor(d2, off);
            d3 += __shfl_xor(d3, off);
        }

        const float sc0 = d0 * smask[rbase + 0];
        const float sc1 = d1 * smask[rbase + 1];
        const float sc2 = d2 * smask[rbase + 2];
        const float sc3 = d3 * smask[rbase + 3];
        if (lane == 0) ssc[rbase + 0] = sc0;
        if (lane == 1) ssc[rbase + 1] = sc1;
        if (lane == 2) ssc[rbase + 2] = sc2;
        if (lane == 3) ssc[rbase + 3] = sc3;

        const float mx = fmaxf(fmaxf(sc0, sc1), fmaxf(sc2, sc3));
        if (mx > m + 8.f) {
            const float e = __expf(m - mx);   // m=-inf -> 0
            l *= e;
            acc_a.x *= e; acc_a.y *= e; acc_a.z *= e; acc_a.w *= e;
            acc_b.x *= e; acc_b.y *= e; acc_b.z *= e; acc_b.w *= e;
            m = mx;
        }
        const float p0 = __expf(sc0 - m);
        const float p1 = __expf(sc1 - m);
        const float p2 = __expf(sc2 - m);
        const float p3 = __expf(sc3 - m);
        l += (p0 + p1) + (p2 + p3);

        {
            float4 c0, c1;
            c0 = *(const float4*)(bp + 0 * HH + lane4);
            c1 = *(const float4*)(bp + 0 * HH + 256 + lane4);
            acc_a.x += p0*c0.x; acc_a.y += p0*c0.y; acc_a.z += p0*c0.z; acc_a.w += p0*c0.w;
            acc_b.x += p0*c1.x; acc_b.y += p0*c1.y; acc_b.z += p0*c1.z; acc_b.w += p0*c1.w;
            c0 = *(const float4*)(bp + 1 * HH + lane4);
            c1 = *(const float4*)(bp + 1 * HH + 256 + lane4);
            acc_a.x += p1*c0.x; acc_a.y += p1*c0.y; acc_a.z += p1*c0.z; acc_a.w += p1*c0.w;
            acc_b.x += p1*c1.x; acc_b.y += p1*c1.y; acc_b.z += p1*c1.z; acc_b.w += p1*c1.w;
            c0 = *(const float4*)(bp + 2 * HH + lane4);
            c1 = *(const float4*)(bp + 2 * HH + 256 + lane4);
            acc_a.x += p2*c0.x; acc_a.y += p2*c0.y; acc_a.z += p2*c0.z; acc_a.w += p2*c0.w;
            acc_b.x += p2*c1.x; acc_b.y += p2*c1.y; acc_b.z += p2*c1.z; acc_b.w += p2*c1.w;
            c0 = *(const float4*)(bp + 3 * HH + lane4);
            c1 = *(const float4*)(bp + 3 * HH + 256 + lane4);
            acc_a.x += p3*c0.x; acc_a.y += p3*c0.y; acc_a.z += p3*c0.z; acc_a.w += p3*c0.w;
            acc_b.x += p3*c1.x; acc_b.y += p3*c1.y; acc_b.z += p3*c1.z; acc_b.w += p3*c1.w;
        }
    }
    #undef ISSUE_TILE

    if (lane == 0) { lm[wave] = m; ll[wave] = l; }
    *(float4*)&lacc[wave][lane4] = acc_a;
    *(float4*)&lacc[wave][256 + lane4] = acc_b;
    __syncthreads();

    const float M = fmaxf(fmaxf(lm[0], lm[1]), fmaxf(lm[2], lm[3]));
    const float e0 = __expf(lm[0] - M);
    const float e1 = __expf(lm[1] - M);
    const float e2 = __expf(lm[2] - M);
    const float e3 = __expf(lm[3] - M);

    float* pml = ws + WS_PML + (size_t)(bi * CHUNKS + chunk) * 2;
    float* pacc = ws + WS_PACC + (size_t)(bi * CHUNKS + chunk) * HH;
    for (int h = threadIdx.x; h < HH; h += 256)
        pacc[h] = lacc[0][h] * e0 + lacc[1][h] * e1 + lacc[2][h] * e2 + lacc[3][h] * e3;
    if (threadIdx.x == 0) {
        pml[0] = M;
        pml[1] = ll[0] * e0 + ll[1] * e1 + ll[2] * e2 + ll[3] * e3;
    }
    if (threadIdx.x < ROWS_PER_BLOCK)
        scores_g[chunk * ROWS_PER_BLOCK + threadIdx.x] = ssc[threadIdx.x];
}

// -------------------- K3: merge partials -> weighted + att ; grid (2,32,4)
__global__ __launch_bounds__(256) void k_merge(
    const float* __restrict__ ws_ro, float* __restrict__ ws, float* __restrict__ out)
{
    const int br = blockIdx.x;
    const int b = blockIdx.y;
    const int hs = blockIdx.z;
    const int bi = br * BB + b;
    const int tid = threadIdx.x;

    const float* pml = ws_ro + WS_PML + (size_t)bi * CHUNKS * 2;
    __shared__ float esc[CHUNKS];
    float M = -INFINITY;
    for (int c = 0; c < CHUNKS; ++c) M = fmaxf(M, pml[2 * c]);
    float L = 0.f;
    for (int c = 0; c < CHUNKS; ++c) L += pml[2 * c + 1] * __expf(pml[2 * c] - M);
    const float invL = 1.f / L;
    if (tid < CHUNKS) esc[tid] = __expf(pml[2 * tid] - M) * invL;
    __syncthreads();

    // weighted slice (128 h per block)
    const float* pacc = ws_ro + WS_PACC + (size_t)bi * CHUNKS * HH;
    float* wt = ws + WS_WEIGHTED + (size_t)bi * HH;
    if (tid < 128) {
        const int h = hs * 128 + tid;
        float a = 0.f;
        for (int c = 0; c < CHUNKS; ++c) a += pacc[(size_t)c * HH + h] * esc[c];
        wt[h] = a;
    }

    // att slice (1024 s per block)
    const float* sc_g = ws_ro + WS_SCORES + (size_t)bi * SS;
    float* att = out + BB * HH + (size_t)bi * SS;
    for (int s = hs * 1024 + tid; s < hs * 1024 + 1024; s += 256)
        att[s] = __expf(sc_g[s] - M) * invL;
}

// -------------------- K4: partial GEMV of combined @ W_out ; grid (8,2,32)
__global__ __launch_bounds__(256) void k_gemv(
    const float* __restrict__ tree_in, const float* __restrict__ text_in,
    const float* __restrict__ W_out, const float* __restrict__ ws_ro,
    float* __restrict__ ws)
{
    const int rc = blockIdx.x;      // 256-row slice of the 2048 rows
    const int half = blockIdx.y;    // 256-col half
    const int b = blockIdx.z;
    const int tid = threadIdx.x;

    // comb = [tree_w | tree_in | text_w | text_in]
    const int seg = rc >> 1;
    const float* src;
    if (seg == 0)      src = ws_ro + WS_WEIGHTED + (size_t)(0 * BB + b) * HH;
    else if (seg == 1) src = tree_in + (size_t)b * HH;
    else if (seg == 2) src = ws_ro + WS_WEIGHTED + (size_t)(1 * BB + b) * HH;
    else               src = text_in + (size_t)b * HH;

    __shared__ float sx[256];
    sx[tid] = src[(rc & 1) * 256 + tid];
    __syncthreads();

    const float* wp = W_out + (size_t)(rc * 256) * HH + half * 256 + tid;
    float a = 0.f;
    #pragma unroll 8
    for (int j = 0; j < 256; ++j)
        a += sx[j] * wp[(size_t)j * HH];

    ws[WS_GPART + (size_t)((rc * 2 + half) * BB + b) * 256 + tid] = a;
}

// -------------------- K5: reduce partials + tanh ; grid (2,32)
__global__ __launch_bounds__(256) void k_fin(
    const float* __restrict__ ws, float* __restrict__ out)
{
    const int half = blockIdx.x;
    const int b = blockIdx.y;
    const int tid = threadIdx.x;
    float v = 0.f;
    #pragma unroll
    for (int rc = 0; rc < 8; ++rc)
        v += ws[WS_GPART + (size_t)((rc * 2 + half) * BB + b) * 256 + tid];
    out[(size_t)b * HH + half * 256 + tid] = tanhf(v);
}

// ---------------------------------------------------------------------- launch
extern "C" void kernel_launch(void* const* d_in, const int* in_sizes, int n_in,
                              void* d_out, int out_size, void* d_ws, size_t ws_size,
                              hipStream_t stream)
{
    const float* tree_inputs  = (const float*)d_in[0];
    const float* tree_context = (const float*)d_in[1];
    const float* text_inputs  = (const float*)d_in[2];
    const float* text_context = (const float*)d_in[3];
    const float* tree_mask    = (const float*)d_in[4];
    const float* text_mask    = (const float*)d_in[5];
    const float* W_in         = (const float*)d_in[6];
    const float* W_out        = (const float*)d_in[7];
    float* out = (float*)d_out;
    float* ws = (float*)d_ws;

    k_target<<<dim3(8, 64), 256, 0, stream>>>(tree_inputs, text_inputs, W_in, ws);
    k_flash<<<dim3(2, CHUNKS, BB), 256, 0, stream>>>(tree_context, text_context,
                                                     tree_mask, text_mask, ws);
    k_merge<<<dim3(2, BB, 4), 256, 0, stream>>>(ws, ws, out);
    k_gemv<<<dim3(8, 2, BB), 256, 0, stream>>>(tree_inputs, text_inputs, W_out, ws, ws);
    k_fin<<<dim3(2, BB), 256, 0, stream>>>(ws, out);
}

// Round 6
// 120.565 us; speedup vs baseline: 2.3930x; 1.0015x over previous
//
#include <hip/hip_runtime.h>
#include <math.h>

#define BB 32
#define SS 4096
#define HH 512
#define CHUNKS 32
#define ROWS_PER_BLOCK 128          // rows per k_flash block
#define ROWS_PER_WAVE 32
#define TROWS 2                     // rows per DMA tile (4 KB)
#define NTILES (ROWS_PER_WAVE / TROWS)   // 16

// ws layout (float offsets):
#define WS_TPART    0               // [8][64][512]  target partials   (262144)
#define WS_SCORES   262144          // [2][B][S]                        (262144)
#define WS_PML      524288          // [2][B][CHUNKS][2]                (4096)
#define WS_PACC     528384          // [2][B][CHUNKS][H]                (1048576)
#define WS_WEIGHTED 1576960         // [2][B][H]                        (32768)
#define WS_GPART    1609728         // [8][2][32][256]                  (131072)

__device__ static inline void gload_lds16(const float* g, float* l) {
    __builtin_amdgcn_global_load_lds(
        (const __attribute__((address_space(1))) void*)g,
        (__attribute__((address_space(3))) void*)l, 16, 0, 0);
}
__device__ static inline void gload_lds16_nt(const float* g, float* l) {
    __builtin_amdgcn_global_load_lds(
        (const __attribute__((address_space(1))) void*)g,
        (__attribute__((address_space(3))) void*)l, 16, 0, 2 /* NT */);
}

// --------------------------------------------- K1: target partial GEMV
__global__ __launch_bounds__(256) void k_target(
    const float* __restrict__ tree_in, const float* __restrict__ text_in,
    const float* __restrict__ W_in, float* __restrict__ ws)
{
    const int rc = blockIdx.x;
    const int bb = blockIdx.y;          // br*32 + b
    const int br = bb >> 5, b = bb & 31;
    const float* inp = (br == 0 ? tree_in : text_in) + b * HH;

    __shared__ float sx[64];
    if (threadIdx.x < 64) sx[threadIdx.x] = inp[rc * 64 + threadIdx.x];
    __syncthreads();

    const int c = threadIdx.x;
    const float* wp = W_in + (size_t)(rc * 64) * HH + c;
    float a0 = 0.f, a1 = 0.f;
    #pragma unroll 8
    for (int j = 0; j < 64; ++j) {
        const float x = sx[j];
        a0 += x * wp[(size_t)j * HH];
        a1 += x * wp[(size_t)j * HH + 256];
    }
    float* tp = ws + WS_TPART + (size_t)(rc * 64 + bb) * HH;
    tp[c] = a0;
    tp[c + 256] = a1;
}

// ------------------------------------------------- K2: flash pass over context
// LDS: tiles 4 waves x 2 bufs x 1024 floats = 32 KB; +smask/ssc/lm/ll ~1 KB.
// lacc (end-phase) OVERLAYS the tile buffers (dead after last tile).
// => ~33.9 KB/block => 4 blocks/CU = 16 waves/CU.
__global__ __launch_bounds__(256) void k_flash(
    const float* __restrict__ tree_ctx, const float* __restrict__ text_ctx,
    const float* __restrict__ tree_mask, const float* __restrict__ text_mask,
    float* __restrict__ ws)
{
    const int br = blockIdx.x;          // fastest: mixes L3-tree and NT-text blocks
    const int chunk = blockIdx.y;
    const int b = blockIdx.z;
    const int bi = br * BB + b;

    const float* ctx = (br == 0 ? tree_ctx : text_ctx) + (size_t)b * SS * HH;
    const float* mask = (br == 0 ? tree_mask : text_mask) + (size_t)b * SS;
    float* scores_g = ws + WS_SCORES + (size_t)bi * SS;

    const int wave = threadIdx.x >> 6;
    const int lane = threadIdx.x & 63;
    const int lane4 = lane * 4;

    __shared__ float smem[4 * 2 * 1024 + 128 + 128 + 8 + 8];  // 33.9 KB
    float* const tiles_w = smem + wave * 2048;                 // [2][1024]
    float* const smask = smem + 8192;
    float* const ssc = smem + 8320;
    float* const lm = smem + 8448;
    float* const ll = smem + 8456;

    float* const buf0 = tiles_w;
    float* const buf1 = tiles_w + 1024;
    const int s0 = chunk * ROWS_PER_BLOCK + wave * ROWS_PER_WAVE;
    const int r0 = wave * ROWS_PER_WAVE;

    // 2-row (4 KB) tile = 4 DMA instrs; rows contiguous in memory
    #define ISSUE_TILE(TT, BP) do {                                          \
        const float* _g = ctx + (size_t)(s0 + (TT) * TROWS) * HH + lane4;    \
        if (br == 0) {                                                       \
            _Pragma("unroll")                                                \
            for (int j = 0; j < 4; ++j)                                      \
                gload_lds16(_g + j * 256, (BP) + j * 256);                   \
        } else {                                                             \
            _Pragma("unroll")                                                \
            for (int j = 0; j < 4; ++j)                                      \
                gload_lds16_nt(_g + j * 256, (BP) + j * 256);                \
        }                                                                    \
    } while (0)

    // start DMA pipeline first so tile0 streams under the target fetch
    ISSUE_TILE(0, buf0);
    __builtin_amdgcn_sched_barrier(0);

    if (threadIdx.x < ROWS_PER_BLOCK)
        smask[threadIdx.x] = mask[chunk * ROWS_PER_BLOCK + threadIdx.x];

    // target fragment = sum of 8 partials
    float4 t0 = make_float4(0.f, 0.f, 0.f, 0.f);
    float4 t1 = make_float4(0.f, 0.f, 0.f, 0.f);
    #pragma unroll
    for (int rc = 0; rc < 8; ++rc) {
        const float* tp = ws + WS_TPART + (size_t)(rc * 64 + bi) * HH;
        const float4 u = *(const float4*)(tp + lane4);
        const float4 v = *(const float4*)(tp + 256 + lane4);
        t0.x += u.x; t0.y += u.y; t0.z += u.z; t0.w += u.w;
        t1.x += v.x; t1.y += v.y; t1.z += v.z; t1.w += v.w;
    }
    __syncthreads();   // drains vmem (tile0 landed), smask visible

    float m = -INFINITY, l = 0.f;
    float4 acc_a = make_float4(0.f, 0.f, 0.f, 0.f);
    float4 acc_b = make_float4(0.f, 0.f, 0.f, 0.f);

    for (int tt = 0; tt < NTILES; ++tt) {
        if (tt + 1 < NTILES) {
            float* nb = ((tt + 1) & 1) ? buf1 : buf0;
            ISSUE_TILE(tt + 1, nb);
            asm volatile("s_waitcnt vmcnt(4)" ::: "memory");
        } else {
            asm volatile("s_waitcnt vmcnt(0)" ::: "memory");
        }
        __builtin_amdgcn_sched_barrier(0);

        const float* bp = (tt & 1) ? buf1 : buf0;
        const int rbase = r0 + tt * TROWS;

        // single LDS read; tile kept in registers for the weighted pass
        const float4 c00 = *(const float4*)(bp + lane4);
        const float4 c01 = *(const float4*)(bp + 256 + lane4);
        const float4 c10 = *(const float4*)(bp + 512 + lane4);
        const float4 c11 = *(const float4*)(bp + 768 + lane4);

        float d0 = c00.x*t0.x + c00.y*t0.y + c00.z*t0.z + c00.w*t0.w
                 + c01.x*t1.x + c01.y*t1.y + c01.z*t1.z + c01.w*t1.w;
        float d1 = c10.x*t0.x + c10.y*t0.y + c10.z*t0.z + c10.w*t0.w
                 + c11.x*t1.x + c11.y*t1.y + c11.z*t1.z + c11.w*t1.w;
        #pragma unroll
        for (int off = 1; off < 64; off <<= 1) {
            d0 += __shfl_xor(d0, off);
            d1 += __shfl_xor(d1, off);
        }

        const float sc0 = d0 * smask[rbase + 0];
        const float sc1 = d1 * smask[rbase + 1];
        if (lane == 0) ssc[rbase + 0] = sc0;
        if (lane == 1) ssc[rbase + 1] = sc1;

        const float mx = fmaxf(sc0, sc1);
        if (mx > m + 8.f) {                 // deferred-max rescale
            const float e = __expf(m - mx); // m==-inf -> 0
            l *= e;
            acc_a.x *= e; acc_a.y *= e; acc_a.z *= e; acc_a.w *= e;
            acc_b.x *= e; acc_b.y *= e; acc_b.z *= e; acc_b.w *= e;
            m = mx;
        }
        const float p0 = __expf(sc0 - m);
        const float p1 = __expf(sc1 - m);
        l += p0 + p1;

        acc_a.x += p0*c00.x + p1*c10.x;
        acc_a.y += p0*c00.y + p1*c10.y;
        acc_a.z += p0*c00.z + p1*c10.z;
        acc_a.w += p0*c00.w + p1*c10.w;
        acc_b.x += p0*c01.x + p1*c11.x;
        acc_b.y += p0*c01.y + p1*c11.y;
        acc_b.z += p0*c01.z + p1*c11.z;
        acc_b.w += p0*c01.w + p1*c11.w;
    }
    #undef ISSUE_TILE

    // end phase: lacc overlays each wave's (now dead) tile buffers
    __syncthreads();                         // all waves done with tiles
    float* const lacc_w = tiles_w;           // 512 floats per wave
    if (lane == 0) { lm[wave] = m; ll[wave] = l; }
    *(float4*)(lacc_w + lane4) = acc_a;
    *(float4*)(lacc_w + 256 + lane4) = acc_b;
    __syncthreads();

    const float M = fmaxf(fmaxf(lm[0], lm[1]), fmaxf(lm[2], lm[3]));
    const float e0 = __expf(lm[0] - M);
    const float e1 = __expf(lm[1] - M);
    const float e2 = __expf(lm[2] - M);
    const float e3 = __expf(lm[3] - M);

    float* pml = ws + WS_PML + (size_t)(bi * CHUNKS + chunk) * 2;
    float* pacc = ws + WS_PACC + (size_t)(bi * CHUNKS + chunk) * HH;
    for (int h = threadIdx.x; h < HH; h += 256)
        pacc[h] = smem[0 * 2048 + h] * e0 + smem[1 * 2048 + h] * e1
                + smem[2 * 2048 + h] * e2 + smem[3 * 2048 + h] * e3;
    if (threadIdx.x == 0) {
        pml[0] = M;
        pml[1] = ll[0] * e0 + ll[1] * e1 + ll[2] * e2 + ll[3] * e3;
    }
    if (threadIdx.x < ROWS_PER_BLOCK)
        scores_g[chunk * ROWS_PER_BLOCK + threadIdx.x] = ssc[threadIdx.x];
}

// -------------------- K3: merge partials -> weighted + att ; grid (2,32,4)
__global__ __launch_bounds__(256) void k_merge(
    const float* __restrict__ ws_ro, float* __restrict__ ws, float* __restrict__ out)
{
    const int br = blockIdx.x;
    const int b = blockIdx.y;
    const int hs = blockIdx.z;
    const int bi = br * BB + b;
    const int tid = threadIdx.x;

    const float* pml = ws_ro + WS_PML + (size_t)bi * CHUNKS * 2;
    __shared__ float esc[CHUNKS];
    float M = -INFINITY;
    for (int c = 0; c < CHUNKS; ++c) M = fmaxf(M, pml[2 * c]);
    float L = 0.f;
    for (int c = 0; c < CHUNKS; ++c) L += pml[2 * c + 1] * __expf(pml[2 * c] - M);
    const float invL = 1.f / L;
    if (tid < CHUNKS) esc[tid] = __expf(pml[2 * tid] - M) * invL;
    __syncthreads();

    const float* pacc = ws_ro + WS_PACC + (size_t)bi * CHUNKS * HH;
    float* wt = ws + WS_WEIGHTED + (size_t)bi * HH;
    if (tid < 128) {
        const int h = hs * 128 + tid;
        float a = 0.f;
        for (int c = 0; c < CHUNKS; ++c) a += pacc[(size_t)c * HH + h] * esc[c];
        wt[h] = a;
    }

    const float* sc_g = ws_ro + WS_SCORES + (size_t)bi * SS;
    float* att = out + BB * HH + (size_t)bi * SS;
    for (int s = hs * 1024 + tid; s < hs * 1024 + 1024; s += 256)
        att[s] = __expf(sc_g[s] - M) * invL;
}

// -------------------- K4: partial GEMV of combined @ W_out ; grid (8,2,32)
__global__ __launch_bounds__(256) void k_gemv(
    const float* __restrict__ tree_in, const float* __restrict__ text_in,
    const float* __restrict__ W_out, const float* __restrict__ ws_ro,
    float* __restrict__ ws)
{
    const int rc = blockIdx.x;      // 256-row slice of the 2048 rows
    const int half = blockIdx.y;    // 256-col half
    const int b = blockIdx.z;
    const int tid = threadIdx.x;

    const int seg = rc >> 1;
    const float* src;
    if (seg == 0)      src = ws_ro + WS_WEIGHTED + (size_t)(0 * BB + b) * HH;
    else if (seg == 1) src = tree_in + (size_t)b * HH;
    else if (seg == 2) src = ws_ro + WS_WEIGHTED + (size_t)(1 * BB + b) * HH;
    else               src = text_in + (size_t)b * HH;

    __shared__ float sx[256];
    sx[tid] = src[(rc & 1) * 256 + tid];
    __syncthreads();

    const float* wp = W_out + (size_t)(rc * 256) * HH + half * 256 + tid;
    float a = 0.f;
    #pragma unroll 8
    for (int j = 0; j < 256; ++j)
        a += sx[j] * wp[(size_t)j * HH];

    ws[WS_GPART + (size_t)((rc * 2 + half) * BB + b) * 256 + tid] = a;
}

// -------------------- K5: reduce partials + tanh ; grid (2,32)
__global__ __launch_bounds__(256) void k_fin(
    const float* __restrict__ ws, float* __restrict__ out)
{
    const int half = blockIdx.x;
    const int b = blockIdx.y;
    const int tid = threadIdx.x;
    float v = 0.f;
    #pragma unroll
    for (int rc = 0; rc < 8; ++rc)
        v += ws[WS_GPART + (size_t)((rc * 2 + half) * BB + b) * 256 + tid];
    out[(size_t)b * HH + half * 256 + tid] = tanhf(v);
}

// ---------------------------------------------------------------------- launch
extern "C" void kernel_launch(void* const* d_in, const int* in_sizes, int n_in,
                              void* d_out, int out_size, void* d_ws, size_t ws_size,
                              hipStream_t stream)
{
    const float* tree_inputs  = (const float*)d_in[0];
    const float* tree_context = (const float*)d_in[1];
    const float* text_inputs  = (const float*)d_in[2];
    const float* text_context = (const float*)d_in[3];
    const float* tree_mask    = (const float*)d_in[4];
    const float* text_mask    = (const float*)d_in[5];
    const float* W_in         = (const float*)d_in[6];
    const float* W_out        = (const float*)d_in[7];
    float* out = (float*)d_out;
    float* ws = (float*)d_ws;

    k_target<<<dim3(8, 64), 256, 0, stream>>>(tree_inputs, text_inputs, W_in, ws);
    k_flash<<<dim3(2, CHUNKS, BB), 256, 0, stream>>>(tree_context, text_context,
                                                     tree_mask, text_mask, ws);
    k_merge<<<dim3(2, BB, 4), 256, 0, stream>>>(ws, ws, out);
    k_gemv<<<dim3(8, 2, BB), 256, 0, stream>>>(tree_inputs, text_inputs, W_out, ws, ws);
    k_fin<<<dim3(2, BB), 256, 0, stream>>>(ws, out);
}

// Round 7
// 112.848 us; speedup vs baseline: 2.5567x; 1.0684x over previous
//
#include <hip/hip_runtime.h>
#include <math.h>

#define BB 32
#define SS 4096
#define HH 512
#define CHUNKS 32
#define ROWS_PER_BLOCK 128          // rows per k_flash block
#define ROWS_PER_WAVE 32
#define TROWS 2                     // rows per DMA tile (4 KB)
#define NTILES (ROWS_PER_WAVE / TROWS)   // 16

// ws layout (float offsets):
#define WS_TPART    0               // [8][64][512]  target partials   (262144)
#define WS_SCORES   262144          // [2][B][S]                        (262144)
#define WS_PML      524288          // [2][B][CHUNKS][2]                (4096)
#define WS_PACC     528384          // [2][B][CHUNKS][H]                (1048576)
#define WS_WEIGHTED 1576960         // [2][B][H]                        (32768)
#define WS_GPART    1609728         // [16][2][32][256]                 (262144)

__device__ static inline void gload_lds16(const float* g, float* l) {
    __builtin_amdgcn_global_load_lds(
        (const __attribute__((address_space(1))) void*)g,
        (__attribute__((address_space(3))) void*)l, 16, 0, 0);
}
__device__ static inline void gload_lds16_nt(const float* g, float* l) {
    __builtin_amdgcn_global_load_lds(
        (const __attribute__((address_space(1))) void*)g,
        (__attribute__((address_space(3))) void*)l, 16, 0, 2 /* NT */);
}

// --------------------------------------------- K1: target partial GEMV
__global__ __launch_bounds__(256) void k_target(
    const float* __restrict__ tree_in, const float* __restrict__ text_in,
    const float* __restrict__ W_in, float* __restrict__ ws)
{
    const int rc = blockIdx.x;
    const int bb = blockIdx.y;          // br*32 + b
    const int br = bb >> 5, b = bb & 31;
    const float* inp = (br == 0 ? tree_in : text_in) + b * HH;

    __shared__ float sx[64];
    if (threadIdx.x < 64) sx[threadIdx.x] = inp[rc * 64 + threadIdx.x];
    __syncthreads();

    const int c = threadIdx.x;
    const float* wp = W_in + (size_t)(rc * 64) * HH + c;
    float a0 = 0.f, a1 = 0.f;
    #pragma unroll 8
    for (int j = 0; j < 64; ++j) {
        const float x = sx[j];
        a0 += x * wp[(size_t)j * HH];
        a1 += x * wp[(size_t)j * HH + 256];
    }
    float* tp = ws + WS_TPART + (size_t)(rc * 64 + bb) * HH;
    tp[c] = a0;
    tp[c + 256] = a1;
}

// ------------------------------------------------- K2: flash pass over context
// (unchanged from round 6 — pinned at the delivered-read ceiling)
__global__ __launch_bounds__(256) void k_flash(
    const float* __restrict__ tree_ctx, const float* __restrict__ text_ctx,
    const float* __restrict__ tree_mask, const float* __restrict__ text_mask,
    float* __restrict__ ws)
{
    const int br = blockIdx.x;          // fastest: mixes L3-tree and NT-text blocks
    const int chunk = blockIdx.y;
    const int b = blockIdx.z;
    const int bi = br * BB + b;

    const float* ctx = (br == 0 ? tree_ctx : text_ctx) + (size_t)b * SS * HH;
    const float* mask = (br == 0 ? tree_mask : text_mask) + (size_t)b * SS;
    float* scores_g = ws + WS_SCORES + (size_t)bi * SS;

    const int wave = threadIdx.x >> 6;
    const int lane = threadIdx.x & 63;
    const int lane4 = lane * 4;

    __shared__ float smem[4 * 2 * 1024 + 128 + 128 + 8 + 8];  // 33.9 KB
    float* const tiles_w = smem + wave * 2048;                 // [2][1024]
    float* const smask = smem + 8192;
    float* const ssc = smem + 8320;
    float* const lm = smem + 8448;
    float* const ll = smem + 8456;

    float* const buf0 = tiles_w;
    float* const buf1 = tiles_w + 1024;
    const int s0 = chunk * ROWS_PER_BLOCK + wave * ROWS_PER_WAVE;
    const int r0 = wave * ROWS_PER_WAVE;

    #define ISSUE_TILE(TT, BP) do {                                          \
        const float* _g = ctx + (size_t)(s0 + (TT) * TROWS) * HH + lane4;    \
        if (br == 0) {                                                       \
            _Pragma("unroll")                                                \
            for (int j = 0; j < 4; ++j)                                      \
                gload_lds16(_g + j * 256, (BP) + j * 256);                   \
        } else {                                                             \
            _Pragma("unroll")                                                \
            for (int j = 0; j < 4; ++j)                                      \
                gload_lds16_nt(_g + j * 256, (BP) + j * 256);                \
        }                                                                    \
    } while (0)

    ISSUE_TILE(0, buf0);
    __builtin_amdgcn_sched_barrier(0);

    if (threadIdx.x < ROWS_PER_BLOCK)
        smask[threadIdx.x] = mask[chunk * ROWS_PER_BLOCK + threadIdx.x];

    float4 t0 = make_float4(0.f, 0.f, 0.f, 0.f);
    float4 t1 = make_float4(0.f, 0.f, 0.f, 0.f);
    #pragma unroll
    for (int rc = 0; rc < 8; ++rc) {
        const float* tp = ws + WS_TPART + (size_t)(rc * 64 + bi) * HH;
        const float4 u = *(const float4*)(tp + lane4);
        const float4 v = *(const float4*)(tp + 256 + lane4);
        t0.x += u.x; t0.y += u.y; t0.z += u.z; t0.w += u.w;
        t1.x += v.x; t1.y += v.y; t1.z += v.z; t1.w += v.w;
    }
    __syncthreads();

    float m = -INFINITY, l = 0.f;
    float4 acc_a = make_float4(0.f, 0.f, 0.f, 0.f);
    float4 acc_b = make_float4(0.f, 0.f, 0.f, 0.f);

    for (int tt = 0; tt < NTILES; ++tt) {
        if (tt + 1 < NTILES) {
            float* nb = ((tt + 1) & 1) ? buf1 : buf0;
            ISSUE_TILE(tt + 1, nb);
            asm volatile("s_waitcnt vmcnt(4)" ::: "memory");
        } else {
            asm volatile("s_waitcnt vmcnt(0)" ::: "memory");
        }
        __builtin_amdgcn_sched_barrier(0);

        const float* bp = (tt & 1) ? buf1 : buf0;
        const int rbase = r0 + tt * TROWS;

        const float4 c00 = *(const float4*)(bp + lane4);
        const float4 c01 = *(const float4*)(bp + 256 + lane4);
        const float4 c10 = *(const float4*)(bp + 512 + lane4);
        const float4 c11 = *(const float4*)(bp + 768 + lane4);

        float d0 = c00.x*t0.x + c00.y*t0.y + c00.z*t0.z + c00.w*t0.w
                 + c01.x*t1.x + c01.y*t1.y + c01.z*t1.z + c01.w*t1.w;
        float d1 = c10.x*t0.x + c10.y*t0.y + c10.z*t0.z + c10.w*t0.w
                 + c11.x*t1.x + c11.y*t1.y + c11.z*t1.z + c11.w*t1.w;
        #pragma unroll
        for (int off = 1; off < 64; off <<= 1) {
            d0 += __shfl_xor(d0, off);
            d1 += __shfl_xor(d1, off);
        }

        const float sc0 = d0 * smask[rbase + 0];
        const float sc1 = d1 * smask[rbase + 1];
        if (lane == 0) ssc[rbase + 0] = sc0;
        if (lane == 1) ssc[rbase + 1] = sc1;

        const float mx = fmaxf(sc0, sc1);
        if (mx > m + 8.f) {                 // deferred-max rescale
            const float e = __expf(m - mx); // m==-inf -> 0
            l *= e;
            acc_a.x *= e; acc_a.y *= e; acc_a.z *= e; acc_a.w *= e;
            acc_b.x *= e; acc_b.y *= e; acc_b.z *= e; acc_b.w *= e;
            m = mx;
        }
        const float p0 = __expf(sc0 - m);
        const float p1 = __expf(sc1 - m);
        l += p0 + p1;

        acc_a.x += p0*c00.x + p1*c10.x;
        acc_a.y += p0*c00.y + p1*c10.y;
        acc_a.z += p0*c00.z + p1*c10.z;
        acc_a.w += p0*c00.w + p1*c10.w;
        acc_b.x += p0*c01.x + p1*c11.x;
        acc_b.y += p0*c01.y + p1*c11.y;
        acc_b.z += p0*c01.z + p1*c11.z;
        acc_b.w += p0*c01.w + p1*c11.w;
    }
    #undef ISSUE_TILE

    __syncthreads();                         // all waves done with tiles
    float* const lacc_w = tiles_w;           // overlay: 512 floats per wave
    if (lane == 0) { lm[wave] = m; ll[wave] = l; }
    *(float4*)(lacc_w + lane4) = acc_a;
    *(float4*)(lacc_w + 256 + lane4) = acc_b;
    __syncthreads();

    const float M = fmaxf(fmaxf(lm[0], lm[1]), fmaxf(lm[2], lm[3]));
    const float e0 = __expf(lm[0] - M);
    const float e1 = __expf(lm[1] - M);
    const float e2 = __expf(lm[2] - M);
    const float e3 = __expf(lm[3] - M);

    float* pml = ws + WS_PML + (size_t)(bi * CHUNKS + chunk) * 2;
    float* pacc = ws + WS_PACC + (size_t)(bi * CHUNKS + chunk) * HH;
    for (int h = threadIdx.x; h < HH; h += 256)
        pacc[h] = smem[0 * 2048 + h] * e0 + smem[1 * 2048 + h] * e1
                + smem[2 * 2048 + h] * e2 + smem[3 * 2048 + h] * e3;
    if (threadIdx.x == 0) {
        pml[0] = M;
        pml[1] = ll[0] * e0 + ll[1] * e1 + ll[2] * e2 + ll[3] * e3;
    }
    if (threadIdx.x < ROWS_PER_BLOCK)
        scores_g[chunk * ROWS_PER_BLOCK + threadIdx.x] = ssc[threadIdx.x];
}

// -------------------- K3: merge partials -> weighted + att ; grid (2,32,4)
__global__ __launch_bounds__(256) void k_merge(
    const float* __restrict__ ws_ro, float* __restrict__ ws, float* __restrict__ out)
{
    const int br = blockIdx.x;
    const int b = blockIdx.y;
    const int hs = blockIdx.z;
    const int bi = br * BB + b;
    const int tid = threadIdx.x;

    const float* pml = ws_ro + WS_PML + (size_t)bi * CHUNKS * 2;
    __shared__ float esc[CHUNKS];
    float M = -INFINITY;
    for (int c = 0; c < CHUNKS; ++c) M = fmaxf(M, pml[2 * c]);
    float L = 0.f;
    for (int c = 0; c < CHUNKS; ++c) L += pml[2 * c + 1] * __expf(pml[2 * c] - M);
    const float invL = 1.f / L;
    if (tid < CHUNKS) esc[tid] = __expf(pml[2 * tid] - M) * invL;
    __syncthreads();

    // weighted slice (128 h per block)
    const float* pacc = ws_ro + WS_PACC + (size_t)bi * CHUNKS * HH;
    float* wt = ws + WS_WEIGHTED + (size_t)bi * HH;
    if (tid < 128) {
        const int h = hs * 128 + tid;
        float a = 0.f;
        for (int c = 0; c < CHUNKS; ++c) a += pacc[(size_t)c * HH + h] * esc[c];
        wt[h] = a;
    }

    // att slice (1024 s per block), float4-vectorized
    const float* sc_g = ws_ro + WS_SCORES + (size_t)bi * SS;
    float* att = out + BB * HH + (size_t)bi * SS;
    {
        const int s4 = hs * 1024 + tid * 4;
        const float4 sc = *(const float4*)(sc_g + s4);
        float4 r;
        r.x = __expf(sc.x - M) * invL;
        r.y = __expf(sc.y - M) * invL;
        r.z = __expf(sc.z - M) * invL;
        r.w = __expf(sc.w - M) * invL;
        *(float4*)(att + s4) = r;
    }
}

// -------------------- K4: partial GEMV of combined @ W_out ; grid (16,2,32)
// 16 rc-slices x 128 rows: 128 KB of W_out per block (per-CU read-cap friendly)
__global__ __launch_bounds__(256) void k_gemv(
    const float* __restrict__ tree_in, const float* __restrict__ text_in,
    const float* __restrict__ W_out, const float* __restrict__ ws_ro,
    float* __restrict__ ws)
{
    const int rc = blockIdx.x;      // 128-row slice of the 2048 rows
    const int half = blockIdx.y;    // 256-col half
    const int b = blockIdx.z;
    const int tid = threadIdx.x;

    // comb = [tree_w | tree_in | text_w | text_in], 512 rows per segment
    const int seg = rc >> 2;
    const float* src;
    if (seg == 0)      src = ws_ro + WS_WEIGHTED + (size_t)(0 * BB + b) * HH;
    else if (seg == 1) src = tree_in + (size_t)b * HH;
    else if (seg == 2) src = ws_ro + WS_WEIGHTED + (size_t)(1 * BB + b) * HH;
    else               src = text_in + (size_t)b * HH;

    __shared__ float sx[128];
    if (tid < 128) sx[tid] = src[(rc & 3) * 128 + tid];
    __syncthreads();

    const float* wp = W_out + (size_t)(rc * 128) * HH + half * 256 + tid;
    float a = 0.f;
    #pragma unroll 8
    for (int j = 0; j < 128; ++j)
        a += sx[j] * wp[(size_t)j * HH];

    ws[WS_GPART + (size_t)((rc * 2 + half) * BB + b) * 256 + tid] = a;
}

// -------------------- K5: reduce partials + tanh ; grid (2,32)
__global__ __launch_bounds__(256) void k_fin(
    const float* __restrict__ ws, float* __restrict__ out)
{
    const int half = blockIdx.x;
    const int b = blockIdx.y;
    const int tid = threadIdx.x;
    float v = 0.f;
    #pragma unroll
    for (int rc = 0; rc < 16; ++rc)
        v += ws[WS_GPART + (size_t)((rc * 2 + half) * BB + b) * 256 + tid];
    out[(size_t)b * HH + half * 256 + tid] = tanhf(v);
}

// ---------------------------------------------------------------------- launch
extern "C" void kernel_launch(void* const* d_in, const int* in_sizes, int n_in,
                              void* d_out, int out_size, void* d_ws, size_t ws_size,
                              hipStream_t stream)
{
    const float* tree_inputs  = (const float*)d_in[0];
    const float* tree_context = (const float*)d_in[1];
    const float* text_inputs  = (const float*)d_in[2];
    const float* text_context = (const float*)d_in[3];
    const float* tree_mask    = (const float*)d_in[4];
    const float* text_mask    = (const float*)d_in[5];
    const float* W_in         = (const float*)d_in[6];
    const float* W_out        = (const float*)d_in[7];
    float* out = (float*)d_out;
    float* ws = (float*)d_ws;

    k_target<<<dim3(8, 64), 256, 0, stream>>>(tree_inputs, text_inputs, W_in, ws);
    k_flash<<<dim3(2, CHUNKS, BB), 256, 0, stream>>>(tree_context, text_context,
                                                     tree_mask, text_mask, ws);
    k_merge<<<dim3(2, BB, 4), 256, 0, stream>>>(ws, ws, out);
    k_gemv<<<dim3(16, 2, BB), 256, 0, stream>>>(tree_inputs, text_inputs, W_out, ws, ws);
    k_fin<<<dim3(2, BB), 256, 0, stream>>>(ws, out);
}